// Round 11
// baseline (358.201 us; speedup 1.0000x reference)
//
#include <hip/hip_runtime.h>

// Problem constants (fixed by the reference)
#define BB 2
#define LL 2048
#define SS 2048
#define HH 16
#define EE 64
#define HE (HH*EE)          // fp32 elements per token row: 1024
#define BL 128              // l-rows per band
#define TS 64               // s-cols per tile
#define NT2 32              // 64-col tiles across S
#define SCALEF 0.125f       // 1/sqrt(64)
#define NEGBIG (-1e30f)     // -inf stand-in; exp underflows to exact 0

typedef __bf16 bf8 __attribute__((ext_vector_type(8)));
typedef float f4v __attribute__((ext_vector_type(4)));
typedef unsigned int u32;
typedef unsigned short u16;

// d_out layout (fp32 elements): V | A | entropy, concatenated in return order
#define V_ELEMS  ((size_t)BB*LL*HH*EE)              // 4,194,304
#define A_BASE   (V_ELEMS)
#define ENT_BASE (A_BASE + (size_t)BB*HH*LL*SS)     // + 134,217,728

__device__ __forceinline__ u16 bfb(float f) {  // fp32 -> bf16 RNE
    u32 u = __builtin_bit_cast(u32, f);
    return (u16)((u + 0x7fffu + ((u >> 16) & 1u)) >> 16);
}
// XOR swizzle on byte-addr bits 4-6 (LDS bank spread for row-major tiles)
__device__ __forceinline__ int swz8(int r) { return (((r) & 7) ^ (((r) >> 3) & 7)) << 4; }

__device__ __forceinline__ f4v mfma16(bf8 a, bf8 b, f4v c) {
    return __builtin_amdgcn_mfma_f32_16x16x32_bf16(a, b, c, 0, 0, 0);
}
// Masks may arrive as 1-byte bool or 4-byte int32 — runtime-detected.
__device__ __forceinline__ int maskv(const void* p, int i, int isB) {
    return isB ? (int)((const unsigned char*)p)[i] : ((const int*)p)[i];
}
// LDS-only barrier: waits ds ops, does NOT drain vmcnt — global loads/stores
// stay in flight across it.
__device__ __forceinline__ void barrier_lds() {
    asm volatile("s_waitcnt lgkmcnt(0)" ::: "memory");
    __builtin_amdgcn_s_barrier();
    asm volatile("" ::: "memory");
}
__device__ __forceinline__ uint4 pack8(float4 f0, float4 f1) {  // 8 fp32 -> 8 bf16
    uint4 wv;
    wv.x = bfb(f0.x) | ((u32)bfb(f0.y) << 16);
    wv.y = bfb(f0.z) | ((u32)bfb(f0.w) << 16);
    wv.z = bfb(f1.x) | ((u32)bfb(f1.y) << 16);
    wv.w = bfb(f1.z) | ((u32)bfb(f1.w) << 16);
    return wv;
}
// 8 consecutive fp32 from global -> bf16 MFMA half-fragment (no LDS round-trip).
__device__ __forceinline__ bf8 frag8(const float* p) {
    float4 f0 = *(const float4*)(p);
    float4 f1 = *(const float4*)(p + 4);
    uint4 u = pack8(f0, f1);
    return __builtin_bit_cast(bf8, u);
}

// One block = (b, h, band-pair): bands {pair, 15-pair}, 128 q-rows each. 8
// waves; wave owns 16 q-rows and is INDEPENDENT except for V^T staging:
//  - Pass 1 (stats): K fragments read direct from global (L2-hot) — zero
//    barriers; each wave loops only over its own causal tiles.
//  - Causal zero-tail of A written as contiguous float4 bursts.
//  - Pass 2: K direct from global; P transposed through a wave-PRIVATE 2KB
//    LDS region (own lgkmcnt wait, no barrier); V^T cooperatively staged,
//    double-buffered with register prefetch -> 1 lgkm-barrier per tile.
__global__ __launch_bounds__(512) void k_fused(
    const float* __restrict__ Qg, const float* __restrict__ Kg, const float* __restrict__ Vg,
    const void* __restrict__ mk, const void* __restrict__ mq,
    float* __restrict__ outF)
{
    __shared__ __align__(16) char ldsP[16384];      // 8 wave-private 2KB P regions [16][64] bf16
    __shared__ __align__(16) char ldsVT[2][8192];   // V^T tile dbuf [64 e][64 s] bf16
    __shared__ float ldsKM[SS];                     // k-mask bias row (8KB)
    __shared__ int sFlag;

    const int blk = blockIdx.x;
    const int bh  = (blk & 7) + (((blk >> 3) & 3) << 3);  // XCD-major: 4 (b,h) panels per XCD L2
    const int pair = blk >> 5;
    const int b = bh >> 4, h = bh & 15;
    const int tid = threadIdx.x;
    const int w = tid >> 6, lane = tid & 63, g = lane >> 4, le = lane & 15;

    // ---- mask element-width detection (1B bool vs 4B int32), first 4KB of mk ----
    int isB;
    {
        const unsigned char* c = (const unsigned char*)mk;
        unsigned acc = 0;
        #pragma unroll
        for (int j = 0; j < 8; ++j) {
            const int off = tid + j * 512;
            if (off & 3) acc |= c[off];   // int32 0/1 data: all these bytes are 0
        }
        if (tid == 0) sFlag = 0;
        __syncthreads();
        if (acc) atomicOr(&sFlag, 1);
        __syncthreads();
        isB = sFlag;
    }
    // ---- preload the whole k-mask row once ----
    for (int i = tid; i < SS; i += 512)
        ldsKM[i] = maskv(mk, b * SS + i, isB) ? NEGBIG : 0.f;
    __syncthreads();

    const float* Qb = Qg + (size_t)b * LL * HE + h * EE;
    const float* Kb = Kg + (size_t)b * SS * HE + h * EE;
    const float* Vb = Vg + (size_t)b * SS * HE + h * EE;

    // V^T stager geometry (cooperative): 32 row-pairs x 16 e-quads
    const int vrp = tid >> 4, vei = tid & 15;
    const float* vbase = Vb + (size_t)(2 * vrp) * HE + vei * 4;
    char* const myP = ldsP + w * 2048;                  // wave-private P region
    // per-lane K row base: row le, cols g*8.. (fragment layout)
    const float* krow0 = Kb + (size_t)le * HE + g * 8;

    for (int bi = 0; bi < 2; ++bi) {
        const int band = bi ? (15 - pair) : pair;
        const int l0 = band * BL;
        const int lbase = l0 + w * 16 + g * 4;   // this lane's 4 C-layout rows
        const int ta = (l0 + w * 16 + 15) >> 6;  // wave's last causal tile index
        const int ntile = 2 * (band + 1);        // block-level causal tiles

        // ---- Q fragments direct from global (no LDS, no barrier) ----
        const float* qrow = Qb + (size_t)(l0 + w * 16 + le) * HE + g * 8;
        bf8 qf0 = frag8(qrow);
        bf8 qf1 = frag8(qrow + 32);

        // ================= PASS 1: per-row M, D, T — BARRIER-FREE =================
        float M[4], D[4], T[4];
        #pragma unroll
        for (int r = 0; r < 4; ++r) { M[r] = NEGBIG; D[r] = 0.f; T[r] = 0.f; }

        for (int st = 0; st <= ta; ++st) {
            const int s0 = st * TS;
            const float* kt = krow0 + (size_t)s0 * HE;
            f4v acc[4];
            float tm[4] = {NEGBIG, NEGBIG, NEGBIG, NEGBIG};
            #pragma unroll
            for (int cb = 0; cb < 4; ++cb) {
                const float* kp = kt + (size_t)(cb * 16) * HE;
                bf8 k0 = frag8(kp);
                bf8 k1 = frag8(kp + 32);
                f4v a = {0.f, 0.f, 0.f, 0.f};
                a = mfma16(qf0, k0, a);
                a = mfma16(qf1, k1, a);
                const float km = ldsKM[s0 + cb * 16 + le];
                const int s = s0 + cb * 16 + le;
                #pragma unroll
                for (int r = 0; r < 4; ++r) {
                    float z = a[r] * SCALEF + km;       // scale*(score + m_k)
                    if (s > lbase + r) z = NEGBIG;      // causal (pos == arange)
                    acc[cb][r] = z;
                    tm[r] = fmaxf(tm[r], z);
                }
            }
            // tile-level rescale: one shared max per row-tile, 1 exp per element
            #pragma unroll
            for (int r = 0; r < 4; ++r) {
                #pragma unroll
                for (int msk = 1; msk < 16; msk <<= 1)
                    tm[r] = fmaxf(tm[r], __shfl_xor(tm[r], msk));
                const float mn  = fmaxf(M[r], tm[r]);
                const float fre = __expf(M[r] - mn);    // 0 when jumping off -1e30
                float ed = 0.f, et = 0.f;
                #pragma unroll
                for (int cb = 0; cb < 4; ++cb) {
                    const float z = acc[cb][r];
                    const float e = __expf(z - mn);
                    ed += e; et += e * z;
                }
                D[r] = D[r] * fre + ed;
                T[r] = T[r] * fre + et;
                M[r] = mn;
            }
        }

        // butterfly-merge over the 16-lane group; C = logsumexp, entropy out
        float C[4];
        #pragma unroll
        for (int r = 0; r < 4; ++r) {
            #pragma unroll
            for (int msk = 1; msk < 16; msk <<= 1) {
                const float Mo = __shfl_xor(M[r], msk);
                const float Do = __shfl_xor(D[r], msk);
                const float To = __shfl_xor(T[r], msk);
                const float mn = fmaxf(M[r], Mo);
                const float fa = __expf(M[r] - mn);
                const float fb = __expf(Mo  - mn);
                D[r] = D[r] * fa + Do * fb;
                T[r] = T[r] * fa + To * fb;
                M[r] = mn;
            }
            const int l = lbase + r;
            const bool valid = (M[r] > -1e29f) && (maskv(mq, b * LL + l, isB) == 0);
            C[r] = valid ? (M[r] + __logf(D[r])) : 1e30f;     // p = exp(z - C); dead rows -> 0
            const float ent = valid ? (C[r] - T[r] / D[r]) : 0.f;
            if (le == 0) outF[ENT_BASE + (size_t)bh * LL + l] = ent;
        }

        float* const Arow0 = outF + A_BASE + ((size_t)bh * LL + l0) * SS;

        // ---- causal zero-tail: contiguous float4 bursts (tiles > ta are exactly 0) ----
        {
            const int rr = lane >> 2, cc = lane & 3;     // 4 lanes per row
            float* dst0 = Arow0 + (size_t)(w * 16 + rr) * SS;
            const f4v zz = {0.f, 0.f, 0.f, 0.f};
            for (int c = (ta + 1) * TS + cc * 4; c < SS; c += 16)
                *(f4v*)(void*)(dst0 + c) = zz;
        }

        // ================= PASS 2: A (fp32) + O = A·V — 1 barrier/tile =================
        f4v O[4];
        #pragma unroll
        for (int eb = 0; eb < 4; ++eb) O[eb] = (f4v){0.f, 0.f, 0.f, 0.f};

        // V^T prologue: stage tile 0, prefetch tile 1
        float4 va  = *(const float4*)(vbase);
        float4 vb2 = *(const float4*)(vbase + HE);
        {
            const float* pa_ = &va.x; const float* pb_ = &vb2.x;
            #pragma unroll
            for (int i = 0; i < 4; ++i) {
                const int e = vei * 4 + i;
                const u32 pk = (u32)bfb(pa_[i]) | ((u32)bfb(pb_[i]) << 16);
                *(u32*)(void*)(&ldsVT[0][0] + ((e * 128 + vrp * 4) ^ swz8(e))) = pk;
            }
        }
        if (ntile > 1) {
            const float* vp = vbase + (size_t)TS * HE;
            va = *(const float4*)(vp); vb2 = *(const float4*)(vp + HE);
        }
        barrier_lds();   // VT tile 0 visible
        int cur = 0;

        for (int st = 0; st < ntile; ++st) {
            const int s0 = st * TS;
            if (st + 1 < ntile) {   // stage next VT tile from regs, prefetch st+2
                const float* pa_ = &va.x; const float* pb_ = &vb2.x;
                #pragma unroll
                for (int i = 0; i < 4; ++i) {
                    const int e = vei * 4 + i;
                    const u32 pk = (u32)bfb(pa_[i]) | ((u32)bfb(pb_[i]) << 16);
                    *(u32*)(void*)(&ldsVT[cur ^ 1][0] + ((e * 128 + vrp * 4) ^ swz8(e))) = pk;
                }
                if (st + 2 < ntile) {
                    const float* vp = vbase + (size_t)(st + 2) * TS * HE;
                    va = *(const float4*)(vp); vb2 = *(const float4*)(vp + HE);
                }
            }
            if (st <= ta) {   // wave-active tile
                // QK^T — identical instruction sequence to pass 1 -> bit-identical z
                const float* kt = krow0 + (size_t)s0 * HE;
                f4v acc[4];
                #pragma unroll
                for (int cb = 0; cb < 4; ++cb) {
                    const float* kp = kt + (size_t)(cb * 16) * HE;
                    bf8 k0 = frag8(kp);
                    bf8 k1 = frag8(kp + 32);
                    f4v a = {0.f, 0.f, 0.f, 0.f};
                    a = mfma16(qf0, k0, a);
                    a = mfma16(qf1, k1, a);
                    acc[cb] = a;
                }
                // P -> wave-private LDS (bf16) and A -> global (fp32 direct)
                #pragma unroll
                for (int cb = 0; cb < 4; ++cb) {
                    const float km = ldsKM[s0 + cb * 16 + le];
                    const int s = s0 + cb * 16 + le;
                    #pragma unroll
                    for (int r = 0; r < 4; ++r) {
                        float z = acc[cb][r] * SCALEF + km;
                        if (s > lbase + r) z = NEGBIG;
                        const float p = __expf(z - C[r]);   // exact 0 for masked/causal/dead
                        const int row = g * 4 + r;          // wave-local row 0..15
                        *(u16*)(void*)(myP + ((row * 128 + (cb * 16 + le) * 2) ^ swz8(row))) = bfb(p);
                        outF[A_BASE + ((size_t)bh * LL + (l0 + w * 16 + row)) * SS + s] = p;
                    }
                }
                // own-wave P writes complete (no barrier needed: region private)
                asm volatile("s_waitcnt lgkmcnt(0)" ::: "memory");

                // PV: A-frag row = le (wave-local)
                #pragma unroll
                for (int kkb = 0; kkb < 2; ++kkb) {
                    bf8 pa = *(const bf8*)(void*)(myP + ((le * 128 + kkb * 64 + g * 16) ^ swz8(le)));
                    #pragma unroll
                    for (int eb = 0; eb < 4; ++eb) {
                        const int e = eb * 16 + le;
                        bf8 vb = *(const bf8*)(void*)(&ldsVT[cur][0] + ((e * 128 + kkb * 64 + g * 16) ^ swz8(e)));
                        O[eb] = mfma16(pa, vb, O[eb]);
                    }
                }
            }
            barrier_lds();   // VT[cur] reads done everywhere; VT[cur^1] now complete
            cur ^= 1;
        }

        // V output (B,L,H,E) fp32
        #pragma unroll
        for (int eb = 0; eb < 4; ++eb) {
            #pragma unroll
            for (int r = 0; r < 4; ++r) {
                const int l = lbase + r;
                outF[((size_t)(b * LL + l) * HH + h) * EE + eb * 16 + le] = O[eb][r];
            }
        }
        __syncthreads();   // band end: VT/ldsP reuse safe
    }
}

extern "C" void kernel_launch(void* const* d_in, const int* in_sizes, int n_in,
                              void* d_out, int out_size, void* d_ws, size_t ws_size,
                              hipStream_t stream) {
    const float* Q = (const float*)d_in[0];   // fp32
    const float* K = (const float*)d_in[1];
    const float* V = (const float*)d_in[2];
    const void* mk = d_in[3];                 // mask_miss_k (B,S,1), nonzero = missing
    const void* mq = d_in[4];                 // mask_miss_q (B,L,1)
    // d_in[5] = pos (arange -> causal is s > l), d_in[6] = causal_mask (always 1)
    float* outF = (float*)d_out;              // fp32: V | A | entropy

    dim3 blk(512), grid(BB * HH * 8);         // 256 blocks, 8 waves each
    hipLaunchKernelGGL(k_fused, grid, blk, 0, stream, Q, K, V, mk, mq, outF);
}

// Round 12
// 295.928 us; speedup vs baseline: 1.2104x; 1.2104x over previous
//
#include <hip/hip_runtime.h>

// Problem constants (fixed by the reference)
#define BB 2
#define LL 2048
#define SS 2048
#define HH 16
#define EE 64
#define HE (HH*EE)          // fp32 elements per token row: 1024
#define TS 64               // s-cols per tile
#define SCALEF 0.125f       // 1/sqrt(64)
#define NEGBIG (-1e30f)     // -inf stand-in; exp underflows to exact 0

typedef __bf16 bf8 __attribute__((ext_vector_type(8)));
typedef float f4v __attribute__((ext_vector_type(4)));
typedef unsigned int u32;
typedef unsigned short u16;

// d_out layout (fp32 elements): V | A | entropy, concatenated in return order
#define V_ELEMS  ((size_t)BB*LL*HH*EE)              // 4,194,304
#define A_BASE   (V_ELEMS)
#define ENT_BASE (A_BASE + (size_t)BB*HH*LL*SS)     // + 134,217,728

__device__ __forceinline__ u16 bfb(float f) {  // fp32 -> bf16 RNE
    u32 u = __builtin_bit_cast(u32, f);
    return (u16)((u + 0x7fffu + ((u >> 16) & 1u)) >> 16);
}
// XOR swizzle on byte-addr bits 4-6 (LDS bank spread for 128B-row tiles)
__device__ __forceinline__ int swz8(int r) { return (((r) & 7) ^ (((r) >> 3) & 7)) << 4; }

__device__ __forceinline__ f4v mfma16(bf8 a, bf8 b, f4v c) {
    return __builtin_amdgcn_mfma_f32_16x16x32_bf16(a, b, c, 0, 0, 0);
}
// Masks may arrive as 1-byte bool or 4-byte int32 — runtime-detected.
__device__ __forceinline__ int maskv(const void* p, int i, int isB) {
    return isB ? (int)((const unsigned char*)p)[i] : ((const int*)p)[i];
}
// LDS-only barrier: waits ds ops, does NOT drain vmcnt — global loads/stores
// stay in flight across it.
__device__ __forceinline__ void barrier_lds() {
    asm volatile("s_waitcnt lgkmcnt(0)" ::: "memory");
    __builtin_amdgcn_s_barrier();
    asm volatile("" ::: "memory");
}
__device__ __forceinline__ uint4 pack8(float4 f0, float4 f1) {  // 8 fp32 -> 8 bf16
    uint4 wv;
    wv.x = bfb(f0.x) | ((u32)bfb(f0.y) << 16);
    wv.y = bfb(f0.z) | ((u32)bfb(f0.w) << 16);
    wv.z = bfb(f1.x) | ((u32)bfb(f1.y) << 16);
    wv.w = bfb(f1.z) | ((u32)bfb(f1.w) << 16);
    return wv;
}

// Stage a 128x64 fp32 tile (row stride HE) into LDS as bf16 [128][64] swizzled. 512 thr.
__device__ __forceinline__ void stage128x64(const float* __restrict__ src,
                                            char* lds, int tid) {
    const int r = tid >> 2, seg = tid & 3;
    const float* rp = src + (size_t)r * HE + seg * 16;
    float4 f0 = *(const float4*)(rp + 0);
    float4 f1 = *(const float4*)(rp + 4);
    float4 f2 = *(const float4*)(rp + 8);
    float4 f3 = *(const float4*)(rp + 12);
    const int base = r * 128 + seg * 32;
    *(uint4*)(void*)(lds + ((base +  0) ^ swz8(r))) = pack8(f0, f1);
    *(uint4*)(void*)(lds + ((base + 16) ^ swz8(r))) = pack8(f2, f3);
}

// ============================ k_stats =======================================
// 1024 blocks x 256 thr (~4 blocks/CU). One 64-row band per block. Computes
// per-row C = M + lnD -> ws, entropy -> out. Staged-K double-buffer, register
// prefetch, 1 lgkm-barrier per tile. No A traffic.
__global__ __launch_bounds__(256, 4) void k_stats(
    const float* __restrict__ Qg, const float* __restrict__ Kg,
    const void* __restrict__ mk, const void* __restrict__ mq,
    float* __restrict__ outF, float* __restrict__ Cws)
{
    __shared__ __align__(16) char ldsK[2][8192];   // K dbuf [64 s][64 e] bf16 (also Q stage)
    __shared__ float ldsKM[SS];                    // k-mask bias row (8KB)
    __shared__ int sFlag;

    const int blk = blockIdx.x;
    const int xcd = blk & 7, idx = blk >> 3;       // XCD-major
    const int bh  = xcd * 4 + (idx & 3);
    const int band = 31 - (idx >> 2);              // heavy bands first
    const int b = bh >> 4, h = bh & 15;
    const int tid = threadIdx.x;
    const int w = tid >> 6, lane = tid & 63, g = lane >> 4, le = lane & 15;

    int isB;   // mask element-width detection (1B bool vs 4B int32)
    {
        const unsigned char* c = (const unsigned char*)mk;
        unsigned acc = 0;
        #pragma unroll
        for (int j = 0; j < 16; ++j) {
            const int off = tid + j * 256;
            if (off & 3) acc |= c[off];
        }
        if (tid == 0) sFlag = 0;
        __syncthreads();
        if (acc) atomicOr(&sFlag, 1);
        __syncthreads();
        isB = sFlag;
    }
    for (int i = tid; i < SS; i += 256)
        ldsKM[i] = maskv(mk, b * SS + i, isB) ? NEGBIG : 0.f;

    const float* Qb = Qg + (size_t)b * LL * HE + h * EE;
    const float* Kb = Kg + (size_t)b * SS * HE + h * EE;

    const int l0 = band * TS;                  // 64-row band
    const int lbase = l0 + w * 16 + g * 4;
    const int ntile = band + 1;

    // ---- stage Q tile [64][64] into ldsK[0], grab fragments ----
    {
        const int r = tid >> 2, seg = tid & 3;
        const float* rp = Qb + (size_t)(l0 + r) * HE + seg * 16;
        float4 f0 = *(const float4*)(rp + 0);
        float4 f1 = *(const float4*)(rp + 4);
        float4 f2 = *(const float4*)(rp + 8);
        float4 f3 = *(const float4*)(rp + 12);
        const int base = r * 128 + seg * 32;
        *(uint4*)(void*)(&ldsK[0][0] + ((base +  0) ^ swz8(r))) = pack8(f0, f1);
        *(uint4*)(void*)(&ldsK[0][0] + ((base + 16) ^ swz8(r))) = pack8(f2, f3);
    }
    __syncthreads();
    const int qr = w * 16 + le;
    bf8 qf0 = *(const bf8*)(void*)(&ldsK[0][0] + ((qr * 128 +  0 + g * 16) ^ swz8(qr)));
    bf8 qf1 = *(const bf8*)(void*)(&ldsK[0][0] + ((qr * 128 + 64 + g * 16) ^ swz8(qr)));
    barrier_lds();   // all q reads done before K overwrites ldsK[0]

    // ---- K pipeline ----
    const int kr = tid >> 2, ksg = tid & 3;        // 64 rows x 4 segs of 16
    const float* kbase = Kb + (size_t)kr * HE + ksg * 16;
    const int kb0 = kr * 128 + ksg * 32;
    float4 p0 = *(const float4*)(kbase + 0);
    float4 p1 = *(const float4*)(kbase + 4);
    float4 p2 = *(const float4*)(kbase + 8);
    float4 p3 = *(const float4*)(kbase + 12);
    *(uint4*)(void*)(&ldsK[0][0] + ((kb0 +  0) ^ swz8(kr))) = pack8(p0, p1);
    *(uint4*)(void*)(&ldsK[0][0] + ((kb0 + 16) ^ swz8(kr))) = pack8(p2, p3);
    if (ntile > 1) {
        const float* kp = kbase + (size_t)TS * HE;
        p0 = *(const float4*)(kp + 0);  p1 = *(const float4*)(kp + 4);
        p2 = *(const float4*)(kp + 8);  p3 = *(const float4*)(kp + 12);
    }
    barrier_lds();
    int cur = 0;

    float M[4], D[4], T[4];
    #pragma unroll
    for (int r = 0; r < 4; ++r) { M[r] = NEGBIG; D[r] = 0.f; T[r] = 0.f; }

    for (int st = 0; st < ntile; ++st) {
        const int s0 = st * TS;
        if (st + 1 < ntile) {
            *(uint4*)(void*)(&ldsK[cur ^ 1][0] + ((kb0 +  0) ^ swz8(kr))) = pack8(p0, p1);
            *(uint4*)(void*)(&ldsK[cur ^ 1][0] + ((kb0 + 16) ^ swz8(kr))) = pack8(p2, p3);
            if (st + 2 < ntile) {
                const float* kp = kbase + (size_t)(st + 2) * TS * HE;
                p0 = *(const float4*)(kp + 0);  p1 = *(const float4*)(kp + 4);
                p2 = *(const float4*)(kp + 8);  p3 = *(const float4*)(kp + 12);
            }
        }
        f4v acc[4];
        float tm[4] = {NEGBIG, NEGBIG, NEGBIG, NEGBIG};
        #pragma unroll
        for (int cb = 0; cb < 4; ++cb) {
            const int sr = cb * 16 + le;
            bf8 k0 = *(const bf8*)(void*)(&ldsK[cur][0] + ((sr * 128 +  0 + g * 16) ^ swz8(sr)));
            bf8 k1 = *(const bf8*)(void*)(&ldsK[cur][0] + ((sr * 128 + 64 + g * 16) ^ swz8(sr)));
            f4v a = {0.f, 0.f, 0.f, 0.f};
            a = mfma16(qf0, k0, a);
            a = mfma16(qf1, k1, a);
            const float km = ldsKM[s0 + cb * 16 + le];
            const int s = s0 + cb * 16 + le;
            #pragma unroll
            for (int r = 0; r < 4; ++r) {
                float z = a[r] * SCALEF + km;       // scale*(score + m_k)
                if (s > lbase + r) z = NEGBIG;      // causal (pos == arange)
                acc[cb][r] = z;
                tm[r] = fmaxf(tm[r], z);
            }
        }
        #pragma unroll
        for (int r = 0; r < 4; ++r) {
            #pragma unroll
            for (int msk = 1; msk < 16; msk <<= 1)
                tm[r] = fmaxf(tm[r], __shfl_xor(tm[r], msk));
            const float mn  = fmaxf(M[r], tm[r]);
            const float fre = __expf(M[r] - mn);    // 0 when jumping off -1e30
            float ed = 0.f, et = 0.f;
            #pragma unroll
            for (int cb = 0; cb < 4; ++cb) {
                const float z = acc[cb][r];
                const float e = __expf(z - mn);
                ed += e; et += e * z;
            }
            D[r] = D[r] * fre + ed;
            T[r] = T[r] * fre + et;
            M[r] = mn;
        }
        barrier_lds();
        cur ^= 1;
    }

    // butterfly-merge over the 16-lane group; C + entropy out
    #pragma unroll
    for (int r = 0; r < 4; ++r) {
        #pragma unroll
        for (int msk = 1; msk < 16; msk <<= 1) {
            const float Mo = __shfl_xor(M[r], msk);
            const float Do = __shfl_xor(D[r], msk);
            const float To = __shfl_xor(T[r], msk);
            const float mn = fmaxf(M[r], Mo);
            const float fa = __expf(M[r] - mn);
            const float fb = __expf(Mo  - mn);
            D[r] = D[r] * fa + Do * fb;
            T[r] = T[r] * fa + To * fb;
            M[r] = mn;
        }
        const int l = lbase + r;
        const bool valid = (M[r] > -1e29f) && (maskv(mq, b * LL + l, isB) == 0);
        const float C = valid ? (M[r] + __logf(D[r])) : 1e30f;
        const float ent = valid ? (C - T[r] / D[r]) : 0.f;
        if (le == 0) {
            outF[ENT_BASE + (size_t)bh * LL + l] = ent;
            Cws[(size_t)bh * LL + l] = C;
        }
    }
}

// ============================ k_out =========================================
// 512 blocks x 512 thr (2 blocks/CU co-resident). One 128-row band per block,
// heavy-first. Every loop iteration issues A stores -> store pipe stays fed.
// K + V^T staged, double-buffered, register prefetch, 1 lgkm-barrier/tile.
// P goes through a wave-PRIVATE 2KB LDS region (own lgkm wait, no barrier).
__global__ __launch_bounds__(512, 4) void k_out(
    const float* __restrict__ Qg, const float* __restrict__ Kg, const float* __restrict__ Vg,
    const void* __restrict__ mk,
    float* __restrict__ outF, const float* __restrict__ Cws)
{
    __shared__ __align__(16) char ldsP[16384];      // 8 wave-private 2KB P regions [16][64] bf16
    __shared__ __align__(16) char ldsK[2][8192];    // K dbuf [64 s][64 e] bf16 (also Q stage, 16KB)
    __shared__ __align__(16) char ldsVT[2][8192];   // V^T dbuf [64 e][64 s] bf16
    __shared__ float ldsKM[SS];                     // k-mask bias row (8KB)
    __shared__ int sFlag;

    const int blk = blockIdx.x;
    const int xcd = blk & 7, idx = blk >> 3;        // XCD-major
    const int bh  = xcd * 4 + (idx & 3);
    const int band = 15 - (idx >> 2);               // heavy bands first
    const int b = bh >> 4, h = bh & 15;
    const int tid = threadIdx.x;
    const int w = tid >> 6, lane = tid & 63, g = lane >> 4, le = lane & 15;

    int isB;
    {
        const unsigned char* c = (const unsigned char*)mk;
        unsigned acc = 0;
        #pragma unroll
        for (int j = 0; j < 8; ++j) {
            const int off = tid + j * 512;
            if (off & 3) acc |= c[off];
        }
        if (tid == 0) sFlag = 0;
        __syncthreads();
        if (acc) atomicOr(&sFlag, 1);
        __syncthreads();
        isB = sFlag;
    }
    for (int i = tid; i < SS; i += 512)
        ldsKM[i] = maskv(mk, b * SS + i, isB) ? NEGBIG : 0.f;

    const float* Qb = Qg + (size_t)b * LL * HE + h * EE;
    const float* Kb = Kg + (size_t)b * SS * HE + h * EE;
    const float* Vb = Vg + (size_t)b * SS * HE + h * EE;

    const int l0 = band * 128;
    const int lbase = l0 + w * 16 + g * 4;
    const int whi = l0 + w * 16 + 15;
    const int ta  = whi >> 6;                 // wave's last causal tile
    const int ntile = 2 * (band + 1);

    // ---- stage Q tile [128][64] into ldsK (16KB contiguous), grab fragments ----
    stage128x64(Qb + (size_t)l0 * HE, &ldsK[0][0], tid);
    __syncthreads();
    const int qr = w * 16 + le;
    bf8 qf0 = *(const bf8*)(void*)(&ldsK[0][0] + ((qr * 128 +  0 + g * 16) ^ swz8(qr)));
    bf8 qf1 = *(const bf8*)(void*)(&ldsK[0][0] + ((qr * 128 + 64 + g * 16) ^ swz8(qr)));
    float C[4];
    #pragma unroll
    for (int r = 0; r < 4; ++r) C[r] = Cws[(size_t)bh * LL + lbase + r];
    barrier_lds();   // q reads done before K pipeline overwrites

    float* const Arow0 = outF + A_BASE + ((size_t)bh * LL + l0) * SS;

    // ---- causal zero-tail: contiguous float4 bursts (wave's tiles > ta are 0) ----
    {
        const int rr = lane >> 2, cc = lane & 3;
        float* dst0 = Arow0 + (size_t)(w * 16 + rr) * SS;
        const f4v zz = {0.f, 0.f, 0.f, 0.f};
        for (int c = (ta + 1) * TS + cc * 4; c < SS; c += 16)
            *(f4v*)(void*)(dst0 + c) = zz;
    }

    // ---- K/V^T pipeline ----
    const int kr = tid >> 3, ksg = tid & 7;         // K: 64 rows x 8 segs of 8
    const float* kbase = Kb + (size_t)kr * HE + ksg * 8;
    const int koff = (kr * 128 + ksg * 16) ^ swz8(kr);
    const int vrp = tid >> 4, vei = tid & 15;       // V^T: 32 row-pairs x 16 e-quads
    const float* vbase = Vb + (size_t)(2 * vrp) * HE + vei * 4;

    float4 ka  = *(const float4*)(kbase);
    float4 kb2 = *(const float4*)(kbase + 4);
    float4 va  = *(const float4*)(vbase);
    float4 vb2 = *(const float4*)(vbase + HE);
    *(uint4*)(void*)(&ldsK[0][0] + koff) = pack8(ka, kb2);
    {
        const float* pa_ = &va.x; const float* pb_ = &vb2.x;
        #pragma unroll
        for (int i = 0; i < 4; ++i) {
            const int e = vei * 4 + i;
            const u32 pk = (u32)bfb(pa_[i]) | ((u32)bfb(pb_[i]) << 16);
            *(u32*)(void*)(&ldsVT[0][0] + ((e * 128 + vrp * 4) ^ swz8(e))) = pk;
        }
    }
    if (ntile > 1) {
        const float* kp = kbase + (size_t)TS * HE;
        const float* vp = vbase + (size_t)TS * HE;
        ka = *(const float4*)(kp); kb2 = *(const float4*)(kp + 4);
        va = *(const float4*)(vp); vb2 = *(const float4*)(vp + HE);
    }
    barrier_lds();
    int cur = 0;
    char* const myP = ldsP + w * 2048;

    f4v O[4];
    #pragma unroll
    for (int eb = 0; eb < 4; ++eb) O[eb] = (f4v){0.f, 0.f, 0.f, 0.f};

    for (int st = 0; st < ntile; ++st) {
        const int s0 = st * TS;
        if (st + 1 < ntile) {   // stage next tiles from regs, prefetch st+2
            *(uint4*)(void*)(&ldsK[cur ^ 1][0] + koff) = pack8(ka, kb2);
            {
                const float* pa_ = &va.x; const float* pb_ = &vb2.x;
                #pragma unroll
                for (int i = 0; i < 4; ++i) {
                    const int e = vei * 4 + i;
                    const u32 pk = (u32)bfb(pa_[i]) | ((u32)bfb(pb_[i]) << 16);
                    *(u32*)(void*)(&ldsVT[cur ^ 1][0] + ((e * 128 + vrp * 4) ^ swz8(e))) = pk;
                }
            }
            if (st + 2 < ntile) {
                const float* kp = kbase + (size_t)(st + 2) * TS * HE;
                const float* vp = vbase + (size_t)(st + 2) * TS * HE;
                ka = *(const float4*)(kp); kb2 = *(const float4*)(kp + 4);
                va = *(const float4*)(vp); vb2 = *(const float4*)(vp + HE);
            }
        }
        if (st <= ta) {   // wave-active tile
            f4v acc[4];
            #pragma unroll
            for (int cb = 0; cb < 4; ++cb) {
                const int sr = cb * 16 + le;
                bf8 k0 = *(const bf8*)(void*)(&ldsK[cur][0] + ((sr * 128 +  0 + g * 16) ^ swz8(sr)));
                bf8 k1 = *(const bf8*)(void*)(&ldsK[cur][0] + ((sr * 128 + 64 + g * 16) ^ swz8(sr)));
                f4v a = {0.f, 0.f, 0.f, 0.f};
                a = mfma16(qf0, k0, a);
                a = mfma16(qf1, k1, a);
                acc[cb] = a;
            }
            // P -> wave-private LDS (bf16) and A -> global (fp32 direct)
            #pragma unroll
            for (int cb = 0; cb < 4; ++cb) {
                const float km = ldsKM[s0 + cb * 16 + le];
                const int s = s0 + cb * 16 + le;
                #pragma unroll
                for (int r = 0; r < 4; ++r) {
                    float z = acc[cb][r] * SCALEF + km;
                    if (s > lbase + r) z = NEGBIG;
                    const float p = __expf(z - C[r]);   // exact 0 for masked/causal/dead
                    const int row = g * 4 + r;          // wave-local row 0..15
                    *(u16*)(void*)(myP + ((row * 128 + (cb * 16 + le) * 2) ^ swz8(row))) = bfb(p);
                    outF[A_BASE + ((size_t)bh * LL + (l0 + w * 16 + row)) * SS + s] = p;
                }
            }
            asm volatile("s_waitcnt lgkmcnt(0)" ::: "memory");   // own P writes done

            #pragma unroll
            for (int kkb = 0; kkb < 2; ++kkb) {
                bf8 pa = *(const bf8*)(void*)(myP + ((le * 128 + kkb * 64 + g * 16) ^ swz8(le)));
                #pragma unroll
                for (int eb = 0; eb < 4; ++eb) {
                    const int e = eb * 16 + le;
                    bf8 vb = *(const bf8*)(void*)(&ldsVT[cur][0] + ((e * 128 + kkb * 64 + g * 16) ^ swz8(e)));
                    O[eb] = mfma16(pa, vb, O[eb]);
                }
            }
        }
        barrier_lds();   // dbuf[cur] reads done; dbuf[cur^1] writes visible
        cur ^= 1;
    }

    // V output (B,L,H,E) fp32
    #pragma unroll
    for (int eb = 0; eb < 4; ++eb) {
        #pragma unroll
        for (int r = 0; r < 4; ++r) {
            const int l = lbase + r;
            outF[((size_t)(b * LL + l) * HH + h) * EE + eb * 16 + le] = O[eb][r];
        }
    }
}

extern "C" void kernel_launch(void* const* d_in, const int* in_sizes, int n_in,
                              void* d_out, int out_size, void* d_ws, size_t ws_size,
                              hipStream_t stream) {
    const float* Q = (const float*)d_in[0];   // fp32
    const float* K = (const float*)d_in[1];
    const float* V = (const float*)d_in[2];
    const void* mk = d_in[3];                 // mask_miss_k (B,S,1), nonzero = missing
    const void* mq = d_in[4];                 // mask_miss_q (B,L,1)
    // d_in[5] = pos (arange -> causal is s > l), d_in[6] = causal_mask (always 1)
    float* outF = (float*)d_out;              // fp32: V | A | entropy
    float* Cws  = (float*)d_ws;               // per-row logsumexp C (256KB)

    hipLaunchKernelGGL(k_stats, dim3(BB * HH * 32), dim3(256), 0, stream,
                       Q, K, mk, mq, outF, Cws);
    hipLaunchKernelGGL(k_out,   dim3(BB * HH * 16), dim3(512), 0, stream,
                       Q, K, V, mk, outF, Cws);
}

// Round 13
// 221.890 us; speedup vs baseline: 1.6143x; 1.3337x over previous
//
#include <hip/hip_runtime.h>

// Problem constants (fixed by the reference)
#define BB 2
#define LL 2048
#define SS 2048
#define HH 16
#define EE 64
#define HE (HH*EE)          // fp32 elements per token row: 1024
#define TS 64               // s-cols per tile
#define SCALEF 0.125f       // 1/sqrt(64)
#define NEGBIG (-1e30f)     // -inf stand-in; exp underflows to exact 0

typedef __bf16 bf8 __attribute__((ext_vector_type(8)));
typedef float f4v __attribute__((ext_vector_type(4)));
typedef unsigned int u32;
typedef unsigned short u16;

// d_out layout (fp32 elements): V | A | entropy, concatenated in return order
#define V_ELEMS  ((size_t)BB*LL*HH*EE)              // 4,194,304
#define A_BASE   (V_ELEMS)
#define ENT_BASE (A_BASE + (size_t)BB*HH*LL*SS)     // + 134,217,728

__device__ __forceinline__ u16 bfb(float f) {  // fp32 -> bf16 RNE
    u32 u = __builtin_bit_cast(u32, f);
    return (u16)((u + 0x7fffu + ((u >> 16) & 1u)) >> 16);
}
// XOR swizzle on byte-addr bits 4-6 (LDS bank spread for 128B-row tiles)
__device__ __forceinline__ int swz8(int r) { return (((r) & 7) ^ (((r) >> 3) & 7)) << 4; }

__device__ __forceinline__ f4v mfma16(bf8 a, bf8 b, f4v c) {
    return __builtin_amdgcn_mfma_f32_16x16x32_bf16(a, b, c, 0, 0, 0);
}
// Masks may arrive as 1-byte bool or 4-byte int32 — runtime-detected.
__device__ __forceinline__ int maskv(const void* p, int i, int isB) {
    return isB ? (int)((const unsigned char*)p)[i] : ((const int*)p)[i];
}
// LDS-only barrier: waits ds ops, does NOT drain vmcnt — global loads/stores
// stay in flight across it (T14).
__device__ __forceinline__ void barrier_lds() {
    asm volatile("s_waitcnt lgkmcnt(0)" ::: "memory");
    __builtin_amdgcn_s_barrier();
    asm volatile("" ::: "memory");
}
__device__ __forceinline__ uint4 pack8(float4 f0, float4 f1) {  // 8 fp32 -> 8 bf16
    uint4 wv;
    wv.x = bfb(f0.x) | ((u32)bfb(f0.y) << 16);
    wv.y = bfb(f0.z) | ((u32)bfb(f0.w) << 16);
    wv.z = bfb(f1.x) | ((u32)bfb(f1.y) << 16);
    wv.w = bfb(f1.z) | ((u32)bfb(f1.w) << 16);
    return wv;
}

// Stage a 128x64 fp32 tile (row stride HE) into LDS as bf16 [128][64] swizzled. 512 thr.
__device__ __forceinline__ void stage128x64(const float* __restrict__ src,
                                            char* lds, int tid) {
    const int r = tid >> 2, seg = tid & 3;
    const float* rp = src + (size_t)r * HE + seg * 16;
    float4 f0 = *(const float4*)(rp + 0);
    float4 f1 = *(const float4*)(rp + 4);
    float4 f2 = *(const float4*)(rp + 8);
    float4 f3 = *(const float4*)(rp + 12);
    const int base = r * 128 + seg * 32;
    *(uint4*)(void*)(lds + ((base +  0) ^ swz8(r))) = pack8(f0, f1);
    *(uint4*)(void*)(lds + ((base + 16) ^ swz8(r))) = pack8(f2, f3);
}

// One block = (b, h, ONE 128-row band). 512 blocks x 512 thr -> 2 co-resident
// blocks/CU (LDS 56.5KB, VGPR<=128): one block's pass-1 compute overlaps the
// other's pass-2 store bursts. Heavy bands dispatched first (LPT balance).
// Internals = round-10 best: T14 register prefetch, K/V^T LDS double-buffer,
// lgkm-only barriers (1/tile), wave-private P region, causal zero-tail bursts.
__global__ __launch_bounds__(512, 4) void k_fused(
    const float* __restrict__ Qg, const float* __restrict__ Kg, const float* __restrict__ Vg,
    const void* __restrict__ mk, const void* __restrict__ mq,
    float* __restrict__ outF)
{
    __shared__ __align__(16) char ldsP[16384];      // Q stage / 8 wave-private 2KB P regions
    __shared__ __align__(16) char ldsK[2][8192];    // K dbuf [64 s][64 e] bf16
    __shared__ __align__(16) char ldsVT[2][8192];   // V^T dbuf [64 e][64 s] bf16
    __shared__ float ldsKM[SS];                     // k-mask bias row (8KB)
    __shared__ int sFlag;

    // Decode: XCD-major; band heavy-first (band 15 blocks dispatched first).
    const int blk = blockIdx.x;
    const int xcd = blk & 7, idx = blk >> 3;        // idx 0..63
    const int bh  = xcd * 4 + (idx & 3);            // 0..31
    const int band = 15 - (idx >> 2);               // 15..0, heavy first
    const int b = bh >> 4, h = bh & 15;
    const int tid = threadIdx.x;
    const int w = tid >> 6, lane = tid & 63, g = lane >> 4, le = lane & 15;

    int isB;   // mask element-width detection (1B bool vs 4B int32)
    {
        const unsigned char* c = (const unsigned char*)mk;
        unsigned acc = 0;
        #pragma unroll
        for (int j = 0; j < 8; ++j) {
            const int off = tid + j * 512;
            if (off & 3) acc |= c[off];
        }
        if (tid == 0) sFlag = 0;
        __syncthreads();
        if (acc) atomicOr(&sFlag, 1);
        __syncthreads();
        isB = sFlag;
    }
    for (int i = tid; i < SS; i += 512)
        ldsKM[i] = maskv(mk, b * SS + i, isB) ? NEGBIG : 0.f;

    const float* Qb = Qg + (size_t)b * LL * HE + h * EE;
    const float* Kb = Kg + (size_t)b * SS * HE + h * EE;
    const float* Vb = Vg + (size_t)b * SS * HE + h * EE;

    const int l0 = band * 128;
    const int lbase = l0 + w * 16 + g * 4;   // this lane's 4 C-layout rows
    const int whi = l0 + w * 16 + 15;        // wave's highest row
    const int ta  = whi >> 6;                // wave's last causal 64-col tile
    const int ntile = 2 * (band + 1);        // block-level causal tiles

    // ---- stage Q tile [128][64] -> ldsP, grab fragments ----
    stage128x64(Qb + (size_t)l0 * HE, ldsP, tid);
    __syncthreads();
    const int qr = w * 16 + le;
    bf8 qf0 = *(const bf8*)(void*)(ldsP + ((qr * 128 +  0 + g * 16) ^ swz8(qr)));
    bf8 qf1 = *(const bf8*)(void*)(ldsP + ((qr * 128 + 64 + g * 16) ^ swz8(qr)));
    barrier_lds();   // ldsP free for P after this

    // per-thread staging geometry
    const int kr = tid >> 3, ksg = tid & 7;         // K: 64 rows x 8 segs of 8
    const float* kbase = Kb + (size_t)kr * HE + ksg * 8;
    const int koff = (kr * 128 + ksg * 16) ^ swz8(kr);
    const int vrp = tid >> 4, vei = tid & 15;       // V^T: 32 row-pairs x 16 e-quads
    const float* vbase = Vb + (size_t)(2 * vrp) * HE + vei * 4;

    // ================= PASS 1: per-row M, D, T (1 barrier/tile) =================
    float M[4], D[4], T[4];
    #pragma unroll
    for (int r = 0; r < 4; ++r) { M[r] = NEGBIG; D[r] = 0.f; T[r] = 0.f; }

    float4 ka = *(const float4*)(kbase);
    float4 kb2 = *(const float4*)(kbase + 4);
    *(uint4*)(void*)(&ldsK[0][0] + koff) = pack8(ka, kb2);
    if (ntile > 1) {
        const float* kp = kbase + (size_t)TS * HE;
        ka = *(const float4*)(kp); kb2 = *(const float4*)(kp + 4);
    }
    barrier_lds();
    int cur = 0;

    for (int st = 0; st < ntile; ++st) {
        const int s0 = st * TS;
        if (st + 1 < ntile) {   // stage next tile from regs, issue st+2 loads
            *(uint4*)(void*)(&ldsK[cur ^ 1][0] + koff) = pack8(ka, kb2);
            if (st + 2 < ntile) {
                const float* kp = kbase + (size_t)(st + 2) * TS * HE;
                ka = *(const float4*)(kp); kb2 = *(const float4*)(kp + 4);
            }
        }
        if (s0 <= whi) {   // causal skip
            f4v acc[4];
            float tm[4] = {NEGBIG, NEGBIG, NEGBIG, NEGBIG};
            #pragma unroll
            for (int cb = 0; cb < 4; ++cb) {
                const int sr = cb * 16 + le;
                bf8 k0 = *(const bf8*)(void*)(&ldsK[cur][0] + ((sr * 128 +  0 + g * 16) ^ swz8(sr)));
                bf8 k1 = *(const bf8*)(void*)(&ldsK[cur][0] + ((sr * 128 + 64 + g * 16) ^ swz8(sr)));
                f4v a = {0.f, 0.f, 0.f, 0.f};
                a = mfma16(qf0, k0, a);
                a = mfma16(qf1, k1, a);
                const float km = ldsKM[s0 + cb * 16 + le];
                const int s = s0 + cb * 16 + le;
                #pragma unroll
                for (int r = 0; r < 4; ++r) {
                    float z = a[r] * SCALEF + km;       // scale*(score + m_k)
                    if (s > lbase + r) z = NEGBIG;      // causal (pos == arange)
                    acc[cb][r] = z;
                    tm[r] = fmaxf(tm[r], z);
                }
            }
            // tile-level rescale: one shared max per row-tile, 1 exp per element
            #pragma unroll
            for (int r = 0; r < 4; ++r) {
                #pragma unroll
                for (int msk = 1; msk < 16; msk <<= 1)
                    tm[r] = fmaxf(tm[r], __shfl_xor(tm[r], msk));
                const float mn  = fmaxf(M[r], tm[r]);
                const float fre = __expf(M[r] - mn);    // 0 when jumping off -1e30
                float ed = 0.f, et = 0.f;
                #pragma unroll
                for (int cb = 0; cb < 4; ++cb) {
                    const float z = acc[cb][r];
                    const float e = __expf(z - mn);
                    ed += e; et += e * z;
                }
                D[r] = D[r] * fre + ed;
                T[r] = T[r] * fre + et;
                M[r] = mn;
            }
        }
        barrier_lds();
        cur ^= 1;
    }

    // butterfly-merge over the 16-lane group; C = logsumexp, entropy out
    float C[4];
    #pragma unroll
    for (int r = 0; r < 4; ++r) {
        #pragma unroll
        for (int msk = 1; msk < 16; msk <<= 1) {
            const float Mo = __shfl_xor(M[r], msk);
            const float Do = __shfl_xor(D[r], msk);
            const float To = __shfl_xor(T[r], msk);
            const float mn = fmaxf(M[r], Mo);
            const float fa = __expf(M[r] - mn);
            const float fb = __expf(Mo  - mn);
            D[r] = D[r] * fa + Do * fb;
            T[r] = T[r] * fa + To * fb;
            M[r] = mn;
        }
        const int l = lbase + r;
        const bool valid = (M[r] > -1e29f) && (maskv(mq, b * LL + l, isB) == 0);
        C[r] = valid ? (M[r] + __logf(D[r])) : 1e30f;     // p = exp(z - C); dead rows -> 0
        const float ent = valid ? (C[r] - T[r] / D[r]) : 0.f;
        if (le == 0) outF[ENT_BASE + (size_t)bh * LL + l] = ent;
    }

    float* const Arow0 = outF + A_BASE + ((size_t)bh * LL + l0) * SS;

    // ---- causal zero-tail: contiguous float4 bursts (wave's tiles > ta are 0) ----
    {
        const int rr = lane >> 2, cc = lane & 3;
        float* dst0 = Arow0 + (size_t)(w * 16 + rr) * SS;
        const f4v zz = {0.f, 0.f, 0.f, 0.f};
        for (int c = (ta + 1) * TS + cc * 4; c < SS; c += 16)
            *(f4v*)(void*)(dst0 + c) = zz;
    }

    // ================= PASS 2: A (fp32) + O = A·V (1 barrier/tile) =================
    f4v O[4];
    #pragma unroll
    for (int eb = 0; eb < 4; ++eb) O[eb] = (f4v){0.f, 0.f, 0.f, 0.f};

    ka  = *(const float4*)(kbase);
    kb2 = *(const float4*)(kbase + 4);
    float4 va  = *(const float4*)(vbase);
    float4 vb2 = *(const float4*)(vbase + HE);
    *(uint4*)(void*)(&ldsK[0][0] + koff) = pack8(ka, kb2);
    {
        const float* pa_ = &va.x; const float* pb_ = &vb2.x;
        #pragma unroll
        for (int i = 0; i < 4; ++i) {
            const int e = vei * 4 + i;
            const u32 pk = (u32)bfb(pa_[i]) | ((u32)bfb(pb_[i]) << 16);
            *(u32*)(void*)(&ldsVT[0][0] + ((e * 128 + vrp * 4) ^ swz8(e))) = pk;
        }
    }
    if (ntile > 1) {
        const float* kp = kbase + (size_t)TS * HE;
        const float* vp = vbase + (size_t)TS * HE;
        ka = *(const float4*)(kp); kb2 = *(const float4*)(kp + 4);
        va = *(const float4*)(vp); vb2 = *(const float4*)(vp + HE);
    }
    barrier_lds();
    cur = 0;
    char* const myP = ldsP + w * 2048;

    for (int st = 0; st < ntile; ++st) {
        const int s0 = st * TS;
        if (st + 1 < ntile) {   // stage next tiles from regs, prefetch st+2
            *(uint4*)(void*)(&ldsK[cur ^ 1][0] + koff) = pack8(ka, kb2);
            {
                const float* pa_ = &va.x; const float* pb_ = &vb2.x;
                #pragma unroll
                for (int i = 0; i < 4; ++i) {
                    const int e = vei * 4 + i;
                    const u32 pk = (u32)bfb(pa_[i]) | ((u32)bfb(pb_[i]) << 16);
                    *(u32*)(void*)(&ldsVT[cur ^ 1][0] + ((e * 128 + vrp * 4) ^ swz8(e))) = pk;
                }
            }
            if (st + 2 < ntile) {
                const float* kp = kbase + (size_t)(st + 2) * TS * HE;
                const float* vp = vbase + (size_t)(st + 2) * TS * HE;
                ka = *(const float4*)(kp); kb2 = *(const float4*)(kp + 4);
                va = *(const float4*)(vp); vb2 = *(const float4*)(vp + HE);
            }
        }
        if (st <= ta) {   // wave-active tile
            f4v acc[4];
            #pragma unroll
            for (int cb = 0; cb < 4; ++cb) {
                const int sr = cb * 16 + le;
                bf8 k0 = *(const bf8*)(void*)(&ldsK[cur][0] + ((sr * 128 +  0 + g * 16) ^ swz8(sr)));
                bf8 k1 = *(const bf8*)(void*)(&ldsK[cur][0] + ((sr * 128 + 64 + g * 16) ^ swz8(sr)));
                f4v a = {0.f, 0.f, 0.f, 0.f};
                a = mfma16(qf0, k0, a);
                a = mfma16(qf1, k1, a);
                acc[cb] = a;
            }
            // P -> wave-private LDS (bf16) and A -> global (fp32 direct)
            #pragma unroll
            for (int cb = 0; cb < 4; ++cb) {
                const float km = ldsKM[s0 + cb * 16 + le];
                const int s = s0 + cb * 16 + le;
                #pragma unroll
                for (int r = 0; r < 4; ++r) {
                    float z = acc[cb][r] * SCALEF + km;
                    if (s > lbase + r) z = NEGBIG;
                    const float p = __expf(z - C[r]);   // exact 0 for masked/causal/dead
                    const int row = g * 4 + r;          // wave-local row 0..15
                    *(u16*)(void*)(myP + ((row * 128 + (cb * 16 + le) * 2) ^ swz8(row))) = bfb(p);
                    outF[A_BASE + ((size_t)bh * LL + (l0 + w * 16 + row)) * SS + s] = p;
                }
            }
            asm volatile("s_waitcnt lgkmcnt(0)" ::: "memory");   // own P writes done

            #pragma unroll
            for (int kkb = 0; kkb < 2; ++kkb) {
                bf8 pa = *(const bf8*)(void*)(myP + ((le * 128 + kkb * 64 + g * 16) ^ swz8(le)));
                #pragma unroll
                for (int eb = 0; eb < 4; ++eb) {
                    const int e = eb * 16 + le;
                    bf8 vb = *(const bf8*)(void*)(&ldsVT[cur][0] + ((e * 128 + kkb * 64 + g * 16) ^ swz8(e)));
                    O[eb] = mfma16(pa, vb, O[eb]);
                }
            }
        }
        barrier_lds();   // dbuf[cur] reads done; dbuf[cur^1] writes visible
        cur ^= 1;
    }

    // V output (B,L,H,E) fp32
    #pragma unroll
    for (int eb = 0; eb < 4; ++eb) {
        #pragma unroll
        for (int r = 0; r < 4; ++r) {
            const int l = lbase + r;
            outF[((size_t)(b * LL + l) * HH + h) * EE + eb * 16 + le] = O[eb][r];
        }
    }
}

extern "C" void kernel_launch(void* const* d_in, const int* in_sizes, int n_in,
                              void* d_out, int out_size, void* d_ws, size_t ws_size,
                              hipStream_t stream) {
    const float* Q = (const float*)d_in[0];   // fp32
    const float* K = (const float*)d_in[1];
    const float* V = (const float*)d_in[2];
    const void* mk = d_in[3];                 // mask_miss_k (B,S,1), nonzero = missing
    const void* mq = d_in[4];                 // mask_miss_q (B,L,1)
    // d_in[5] = pos (arange -> causal is s > l), d_in[6] = causal_mask (always 1)
    float* outF = (float*)d_out;              // fp32: V | A | entropy

    dim3 blk(512), grid(BB * HH * 16);        // 512 blocks -> 2 co-resident/CU
    hipLaunchKernelGGL(k_fused, grid, blk, 0, stream, Q, K, V, mk, mq, outF);
}